// Round 3
// 425.837 us; speedup vs baseline: 1.0248x; 1.0248x over previous
//
#include <hip/hip_runtime.h>

// CoverageMechanism: out[b,s,v] = logits[b,s,v] - 0.3 * (# occurrences of v
// in tokens[b, s-4 : s]), penalty only for s >= 4.
//
// Shapes (fixed by setup_inputs): B=4, S=512, V=32000.
// Memory-bound pure stream: 262 MB read + 262 MB write => ~83 us floor at
// 6.3 TB/s. Zero reuse of either stream => nontemporal loads/stores (nt
// flag) so the 524 MB working set doesn't thrash L2/L3 (L3 is only 256 MB).
// NOTE: __builtin_nontemporal_* requires a native clang vector type, not
// HIP's float4 class -> use ext_vector_type(4).
// One block per (b,s) row; window tokens are block-uniform scalar loads.
// 8000 float4/row = 31 full 256-thread strides + a 64-thread tail, written
// as a static-trip loop so the compiler can unroll and batch the dwordx4
// loads for MLP.

#define VOCAB_SIZE 32000
#define MAX_REPEAT 4
#define PENALTY_W 0.3f
#define SEQ_LEN 512
#define N4 (VOCAB_SIZE / 4)        // 8000 f32x4 per row
#define FULL_ITERS (N4 / 256)      // 31

typedef float f32x4 __attribute__((ext_vector_type(4)));

#define FIX(idx, vv)                                                         \
    x[idx] -= PENALTY_W * (float)(((vv) == t0) + ((vv) == t1) +              \
                                  ((vv) == t2) + ((vv) == t3))

__global__ __launch_bounds__(256) void coverage_kernel(
    const float* __restrict__ logits,
    const int* __restrict__ tokens,   // harness delivers integer inputs as int32
    float* __restrict__ out)
{
    const int row = blockIdx.x;            // row = b*S + s
    const int s = row & (SEQ_LEN - 1);     // S = 512 (power of two)

    // Window tokens (block-uniform). s < MAX_REPEAT => t = -1 never matches.
    int t0 = -1, t1 = -1, t2 = -1, t3 = -1;
    if (s >= MAX_REPEAT) {
        const int* tp = tokens + row - MAX_REPEAT;  // tokens[b*S + s - 4 ..]
        t0 = tp[0];
        t1 = tp[1];
        t2 = tp[2];
        t3 = tp[3];
    }

    const f32x4* __restrict__ in4 =
        (const f32x4*)(logits + (long long)row * VOCAB_SIZE);
    f32x4* __restrict__ out4 =
        (f32x4*)(out + (long long)row * VOCAB_SIZE);

    int i = threadIdx.x;
    #pragma unroll 4
    for (int k = 0; k < FULL_ITERS; ++k, i += 256) {
        f32x4 x = __builtin_nontemporal_load(&in4[i]);
        const int v = i * 4;
        FIX(0, v);
        FIX(1, v + 1);
        FIX(2, v + 2);
        FIX(3, v + 3);
        __builtin_nontemporal_store(x, &out4[i]);
    }
    // Tail: 8000 - 31*256 = 64 f32x4, threads 0..63.
    if (i < N4) {
        f32x4 x = __builtin_nontemporal_load(&in4[i]);
        const int v = i * 4;
        FIX(0, v);
        FIX(1, v + 1);
        FIX(2, v + 2);
        FIX(3, v + 3);
        __builtin_nontemporal_store(x, &out4[i]);
    }
}

extern "C" void kernel_launch(void* const* d_in, const int* in_sizes, int n_in,
                              void* d_out, int out_size, void* d_ws, size_t ws_size,
                              hipStream_t stream) {
    const float* logits = (const float*)d_in[0];
    const int* tokens = (const int*)d_in[1];
    float* out = (float*)d_out;

    const int rows = in_sizes[1];  // B * S = 2048
    coverage_kernel<<<rows, 256, 0, stream>>>(logits, tokens, out);
}